// Round 3
// baseline (424.731 us; speedup 1.0000x reference)
//
#include <hip/hip_runtime.h>

// ---------------------------------------------------------------------------
// HopfieldLayer via 3x MX-fp8 MFMA GEMMs (mfma_scale_f32_16x16x128_f8f6f4,
// uniform scales = 1.0). Softmax folded: GEMM2 stores F = 32*(exp(beta*l)-1)
// in fp8 + fp32 row sums; GEMM3 computes
// out = (colsum + F@xi/32) / (8192 + rowsum/32) with exact fp32 colsum.
// fp8 outputs are packed 4B/lane -> K-permuted layout (sigma within
// 128-chunks) matched by xi8/xit8 prep; dot products are perm-invariant.
//
// R7: counted-vmcnt 4-phase pipeline, correcting the two identified killers:
//  - R5 failed on XCD-chunk remap (FETCH 43->135MB): use plain ROW-MAJOR
//    block order (the order that measured 43MB in R4).
//  - R6 failed on __syncthreads (= hidden s_waitcnt vmcnt(0)) + occupancy:
//    use RAW s_barrier everywhere; iter-end wait is vmcnt(AL), never 0.
//  Pipeline invariant (1.5 tiles in flight): at iter t start, A(t+1) is in
//  flight; iter t issues B(t+1) (ph0/ph1, into buf^1, freed at iter start)
//  and A(t+2) (ph3, into CURRENT buf after an lgkm(0)+barrier read-fence);
//  iter end: vmcnt(AL) drains A(t+1)+B(t+1), keeps A(t+2) in flight.
//  Latency cover: A = ~5 phases, B = ~3 phases. Tail indices clamp to
//  nkt-1 (in-bounds garbage into never-read regions, uniform vmcnt).
//  - Tiles: GEMM2 256x256 (8 waves 2x4, wave 128x64, LDS 128KB, LDS-port
//    116 B/cyc < 128 limit); GEMM1/3 128x256 (grid 256 = 1 block/CU;
//    256^2 would idle half the GPU at N=1024). B-frags held in registers
//    across phases (each frag read ONCE per iter; R5 re-read 2x).
//  - R4's proven 32B pair-chunk LDS swizzle kept verbatim (conflict counter
//    is constant ~4cyc/b128 across all layouts tried -> counting benign
//    2-way aliasing; not a lever).
// ---------------------------------------------------------------------------

typedef __attribute__((ext_vector_type(8))) int int8v;   // 32 fp8 bytes
typedef __attribute__((ext_vector_type(4))) float f32x4; // MFMA C/D 16x16

#define NDIM 1024
#define NPAT 8192
#define NROW 8192

__device__ __forceinline__ unsigned f8pack4(float a, float b, float c, float d) {
  int w = __builtin_amdgcn_cvt_pk_fp8_f32(a, b, 0, false);
  w = __builtin_amdgcn_cvt_pk_fp8_f32(c, d, w, true);
  return (unsigned)w;
}
__device__ __forceinline__ unsigned char f8b(float v) {
  return (unsigned char)(__builtin_amdgcn_cvt_pk_fp8_f32(v, v, 0, false) & 0xff);
}
// sigma: original col c (0..127) -> packed byte index (epilogue pack order)
__device__ __forceinline__ int sig(int c) {
  return (c & 64) | ((c & 15) << 2) | ((c >> 4) & 3);
}

__device__ __forceinline__ void gload_lds16(const void* g, void* l) {
  __builtin_amdgcn_global_load_lds(
      (const __attribute__((address_space(1))) unsigned char*)g,
      (__attribute__((address_space(3))) unsigned char*)l,
      16, 0, 0);
}

// --------------------------- prep kernels ----------------------------------

__global__ void cast_f8(const float* __restrict__ in,
                        unsigned* __restrict__ out, float scale, int n4) {
  int i = blockIdx.x * blockDim.x + threadIdx.x;
  if (i < n4) {
    float4 v = ((const float4*)in)[i];
    out[i] = f8pack4(v.x * scale, v.y * scale, v.z * scale, v.w * scale);
  }
}

// xi f32 [8192,1024] -> xi8 fp8(32*xi) [8192,1024] (sigma on d within 128),
// xit8 fp8(32*xi) [1024,8192] (sigma on p within 128), colsum[1024] fp32.
__global__ void xi_prep8(const float* __restrict__ xi,
                         unsigned char* __restrict__ xi8,
                         unsigned char* __restrict__ xit8,
                         float* __restrict__ colsum) {
  __shared__ float t[32][33];
  __shared__ float cs[8][32];
  int tx = threadIdx.x, ty = threadIdx.y;
  int d0 = blockIdx.x * 32, p0 = blockIdx.y * 32;
  int d = d0 + tx;
  int di = (d & ~127) + sig(d & 127);
  float psum = 0.f;
#pragma unroll
  for (int j = 0; j < 32; j += 8) {
    float v = xi[(long)(p0 + ty + j) * NDIM + d];
    t[ty + j][tx] = v;
    psum += v;
    xi8[(long)(p0 + ty + j) * NDIM + di] = f8b(32.f * v);
  }
  cs[ty][tx] = psum;
  __syncthreads();
  if (ty == 0) {
    float s = 0.f;
#pragma unroll
    for (int k = 0; k < 8; ++k) s += cs[k][tx];
    atomicAdd(&colsum[d0 + tx], s);
  }
  int p = p0 + tx;
  int pi = (p & ~127) + sig(p & 127);
#pragma unroll
  for (int j = 0; j < 32; j += 8)
    xit8[(long)(d0 + ty + j) * NPAT + pi] = f8b(32.f * t[tx][ty + j]);
}

// --------------------------- 8-wave fp8 GEMM, counted vmcnt ----------------
// acc[m,n] = sum_k A[m,k]*B[n,k]; A:[M,K] fp8, B:[N,K] fp8, K mult of 128.
// BM x 256 tile, 512 thr (8 waves 2x4), wave tile (BM/2) x 64.
// LDS row = 128B = 4 pair-chunks of 32B; pair-chunk p of row r at slot
// p^(r&3); lane operand = one aligned 32B int8v load.
// MODE 0: store fp8(acc/32) packed u32   [GEMM1: q]
// MODE 1: F=32*(exp(beta*acc/32)-1); store fp8(F) packed + rowsum atomics
// MODE 2: store f32 (acc/1024 + colsum[col]) / (8192 + rowsum[row]/32)

#define CLUSTER(P)                                                          \
  __builtin_amdgcn_s_setprio(1);                                            \
  _Pragma("unroll") for (int mt = 0; mt < AP; ++mt)                         \
    _Pragma("unroll") for (int nt = 0; nt < 4; ++nt)                        \
      acc[(P) * AP + mt][nt] =                                              \
          __builtin_amdgcn_mfma_scale_f32_16x16x128_f8f6f4(                 \
              af[mt], bf[nt], acc[(P) * AP + mt][nt], 0, 0, 0, 0x7f7f7f7f,  \
              0, 0x7f7f7f7f);                                               \
  __builtin_amdgcn_s_setprio(0);

template <int MODE, int BM>
__launch_bounds__(512, 2)
__global__ void gemm8(const unsigned char* __restrict__ A,
                      const unsigned char* __restrict__ B,
                      void* __restrict__ Cv, int N, int K,
                      const float* __restrict__ beta_ptr,
                      const float* __restrict__ rowsum,
                      const float* __restrict__ colsum,
                      float* __restrict__ rowsum_out) {
  constexpr int MF = BM / 32;   // m-frags per wave (8 or 4)
  constexpr int AP = MF / 4;    // m-frags per phase (2 or 1)
  constexpr int AL = BM / 64;   // A gloads per thread per tile (4 or 2)
  constexpr int ABYTES = BM * 128;
  constexpr int BUF = ABYTES + 32768;

  __shared__ __attribute__((aligned(16))) unsigned char smem[2 * BUF];

  const int tid = threadIdx.x;
  const int wave = tid >> 6;
  const int lane = tid & 63;
  const int wm = wave >> 2, wn = wave & 3;
  const int quad = lane >> 4, ln = lane & 15;

  // plain row-major block order (the order that measured 43MB FETCH)
  const int nbx = N >> 8;
  const long row0 = (long)(blockIdx.x / nbx) * BM;
  const long col0 = (long)(blockIdx.x % nbx) * 256;
  const int nkt = K >> 7;

  // staging: each gload = 8 rows x 128B; lane -> row lane>>3, slot lane&7.
  // slot s of row r holds global 16B chunk (((s>>1)^(r&3))<<1)|(s&1).
  const int r_in = lane >> 3;
  const int csl = lane & 7;
  const int cg = ((((csl >> 1) ^ (r_in & 3)) << 1) | (csl & 1));
  const unsigned char* pA[AL];
  const unsigned char* pB[4];
  int dA[AL], dB[4];
#pragma unroll
  for (int R = 0; R < AL; ++R) {
    pA[R] = A + (row0 + wave * (BM / 8) + R * 8 + r_in) * (long)K + cg * 16;
    dA[R] = (wave * (BM / 8) + R * 8) * 128;
  }
#pragma unroll
  for (int R = 0; R < 4; ++R) {
    pB[R] = B + (col0 + wave * 32 + R * 8 + r_in) * (long)K + cg * 16;
    dB[R] = ABYTES + (wave * 32 + R * 8) * 128;
  }

  // fragment bases: row = base + f*16 + ln -> row&3 == ln&3; pair-slot
  // (quad^(ln&3)) tile-independent.
  const int ps = (quad ^ (ln & 3)) * 32;
  const int bA = (wm * (BM / 2) + ln) * 128 + ps;
  const int bB = ABYTES + (wn * 64 + ln) * 128 + ps;

  f32x4 acc[MF][4] = {};

  // prologue: A(0),B(0) -> buf0; A(1) -> buf1.A; drain tile0, keep A(1).
#pragma unroll
  for (int R = 0; R < AL; ++R) gload_lds16(pA[R], smem + dA[R]);
#pragma unroll
  for (int R = 0; R < 4; ++R) gload_lds16(pB[R], smem + dB[R]);
#pragma unroll
  for (int R = 0; R < AL; ++R) gload_lds16(pA[R] + 128, smem + BUF + dA[R]);
  asm volatile("s_waitcnt vmcnt(%0)" ::"n"(AL) : "memory");
  __builtin_amdgcn_s_barrier();
  __builtin_amdgcn_sched_barrier(0);

#pragma unroll 2
  for (int i = 0; i < nkt; ++i) {
    const int bo = (i & 1) * BUF;
    const int nbo = BUF - bo;
    const long o1 = (long)(i + 1 < nkt ? i + 1 : nkt - 1) << 7;
    const long o2 = (long)(i + 2 < nkt ? i + 2 : nkt - 1) << 7;
    int8v bf[4], af[AP];

    // ---- ph0: stage B(t+1) half, read all B + A[0..AP), MFMA
    gload_lds16(pB[0] + o1, smem + nbo + dB[0]);
    gload_lds16(pB[1] + o1, smem + nbo + dB[1]);
#pragma unroll
    for (int nt = 0; nt < 4; ++nt)
      bf[nt] = *(const int8v*)(smem + bo + bB + nt * 2048);
#pragma unroll
    for (int t = 0; t < AP; ++t)
      af[t] = *(const int8v*)(smem + bo + bA + t * 2048);
    CLUSTER(0)
    __builtin_amdgcn_s_barrier();

    // ---- ph1: stage B(t+1) other half, read A[AP..2AP), MFMA
    gload_lds16(pB[2] + o1, smem + nbo + dB[2]);
    gload_lds16(pB[3] + o1, smem + nbo + dB[3]);
#pragma unroll
    for (int t = 0; t < AP; ++t)
      af[t] = *(const int8v*)(smem + bo + bA + (AP + t) * 2048);
    CLUSTER(1)
    __builtin_amdgcn_s_barrier();

    // ---- ph2: read A[2AP..3AP), MFMA
#pragma unroll
    for (int t = 0; t < AP; ++t)
      af[t] = *(const int8v*)(smem + bo + bA + (2 * AP + t) * 2048);
    CLUSTER(2)
    __builtin_amdgcn_s_barrier();

    // ---- ph3: read A[3AP..4AP); FENCE (all A reads of this buf complete);
    //           stage A(t+2) into CURRENT buf; MFMA; counted drain.
#pragma unroll
    for (int t = 0; t < AP; ++t)
      af[t] = *(const int8v*)(smem + bo + bA + (3 * AP + t) * 2048);
    asm volatile("s_waitcnt lgkmcnt(0)" ::: "memory");
    __builtin_amdgcn_sched_barrier(0);
    __builtin_amdgcn_s_barrier();
    __builtin_amdgcn_sched_barrier(0);
#pragma unroll
    for (int R = 0; R < AL; ++R)
      gload_lds16(pA[R] + o2, smem + bo + dA[R]);
    CLUSTER(3)
    asm volatile("s_waitcnt vmcnt(%0)" ::"n"(AL) : "memory");
    __builtin_amdgcn_s_barrier();
    __builtin_amdgcn_sched_barrier(0);
  }
  asm volatile("s_waitcnt vmcnt(0)" ::: "memory");  // drain before epilogue

  // ---- epilogue. C/D: col = ln (within 16-tile), row = quad*4 + r. -------
  if (MODE == 0) {
    unsigned* C32 = (unsigned*)Cv;
    const float s = 1.0f / 32.0f;
#pragma unroll
    for (int mf = 0; mf < MF; ++mf)
#pragma unroll
      for (int r = 0; r < 4; ++r) {
        long row = row0 + wm * (BM / 2) + mf * 16 + quad * 4 + r;
        unsigned w = f8pack4(acc[mf][0][r] * s, acc[mf][1][r] * s,
                             acc[mf][2][r] * s, acc[mf][3][r] * s);
        C32[row * (N >> 2) + (col0 >> 2) + wn * 16 + ln] = w;
      }
  } else if (MODE == 1) {
    unsigned* C32 = (unsigned*)Cv;
    const float bs = beta_ptr[0] * (1.0f / 32.0f);
#pragma unroll
    for (int mf = 0; mf < MF; ++mf)
#pragma unroll
      for (int r = 0; r < 4; ++r) {
        long row = row0 + wm * (BM / 2) + mf * 16 + quad * 4 + r;
        float e0 = (__expf(bs * acc[mf][0][r]) - 1.0f) * 32.f;
        float e1 = (__expf(bs * acc[mf][1][r]) - 1.0f) * 32.f;
        float e2 = (__expf(bs * acc[mf][2][r]) - 1.0f) * 32.f;
        float e3 = (__expf(bs * acc[mf][3][r]) - 1.0f) * 32.f;
        C32[row * (N >> 2) + (col0 >> 2) + wn * 16 + ln] =
            f8pack4(e0, e1, e2, e3);
        float s = e0 + e1 + e2 + e3;
        s += __shfl_xor(s, 1, 64);
        s += __shfl_xor(s, 2, 64);
        s += __shfl_xor(s, 4, 64);
        s += __shfl_xor(s, 8, 64);
        if (ln == 0) atomicAdd(&rowsum_out[row], s);
      }
  } else {
    float* C = (float*)Cv;
#pragma unroll
    for (int mf = 0; mf < MF; ++mf)
#pragma unroll
      for (int r = 0; r < 4; ++r) {
        long row = row0 + wm * (BM / 2) + mf * 16 + quad * 4 + r;
        float inv = 1.0f / (8192.0f + rowsum[row] * (1.0f / 32.0f));
#pragma unroll
        for (int nt = 0; nt < 4; ++nt) {
          long col = col0 + wn * 64 + nt * 16 + ln;
          C[row * N + col] =
              (acc[mf][nt][r] * (1.0f / 1024.0f) + colsum[col]) * inv;
        }
      }
  }
}

// --------------------------- launch ----------------------------------------

extern "C" void kernel_launch(void* const* d_in, const int* in_sizes, int n_in,
                              void* d_out, int out_size, void* d_ws,
                              size_t ws_size, hipStream_t stream) {
  const float* x    = (const float*)d_in[0];
  const float* wq   = (const float*)d_in[1];
  const float* xi   = (const float*)d_in[2];
  const float* beta = (const float*)d_in[3];
  float* out = (float*)d_out;

  char* ws = (char*)d_ws;
  const size_t MB = 1024 * 1024;
  unsigned char* x8   = (unsigned char*)(ws);             //  8 MiB
  unsigned char* wq8  = (unsigned char*)(ws + 8 * MB);    //  1 MiB
  unsigned char* q8   = (unsigned char*)(ws + 9 * MB);    //  8 MiB
  unsigned char* xi8  = (unsigned char*)(ws + 17 * MB);   //  8 MiB
  unsigned char* xit8 = (unsigned char*)(ws + 25 * MB);   //  8 MiB
  float*         rs   = (float*)(ws + 33 * MB);           // 32 KiB
  float*         csum = (float*)(ws + 33 * MB + 32768);   //  4 KiB
  unsigned char* E8   = (unsigned char*)(ws + 34 * MB);   // 64 MiB

  hipMemsetAsync(rs, 0, 36864, stream);  // rs + colsum

  cast_f8<<<(NROW * NDIM / 4) / 256, 256, 0, stream>>>(
      x, (unsigned*)x8, 1.0f, NROW * NDIM / 4);
  cast_f8<<<(NDIM * NDIM / 4) / 256, 256, 0, stream>>>(
      wq, (unsigned*)wq8, 32.0f, NDIM * NDIM / 4);
  xi_prep8<<<dim3(NDIM / 32, NPAT / 32), dim3(32, 8), 0, stream>>>(
      xi, xi8, xit8, csum);

  // GEMM1: q = x @ wq^T (acc = 32q), fp8 packed. 128x256 tiles, 256 blocks.
  gemm8<0, 128><<<(NROW / 128) * (NDIM / 256), 512, 0, stream>>>(
      x8, wq8, q8, NDIM, NDIM, nullptr, nullptr, nullptr, nullptr);

  // GEMM2: F = 32*(exp(beta*q.xi)-1), fp8 packed + rowsums. 256x256, 1024.
  gemm8<1, 256><<<(NROW / 256) * (NPAT / 256), 512, 0, stream>>>(
      q8, xi8, E8, NPAT, NDIM, beta, nullptr, nullptr, rs);

  // GEMM3: out = (colsum + F@xi/32) / (8192 + rowsum/32). 128x256, 256.
  gemm8<2, 128><<<(NROW / 128) * (NDIM / 256), 512, 0, stream>>>(
      E8, xit8, out, NDIM, NPAT, nullptr, rs, csum, nullptr);
}